// Round 15
// baseline (169.451 us; speedup 1.0000x reference)
//
#include <hip/hip_runtime.h>
#include <hip/hip_bf16.h>
#include <math.h>

#define NN 262144
#define QQ 256
#define PS 80
#define BB 4096
#define NSLOT 10          // bag spans <= 10 16-row strips (bag>150 rows ~ 12 sigma)
#define RT 16             // rows per strip (1 wave per block)
#define NITER 8           // K tiles of 32

typedef _Float16 f16x8 __attribute__((ext_vector_type(8)));
typedef float f32x4  __attribute__((ext_vector_type(4)));

__device__ inline unsigned short f16b(float f) {
  return __builtin_bit_cast(unsigned short, (_Float16)f);
}
__device__ inline float f16tof(unsigned short u) {
  return (float)__builtin_bit_cast(_Float16, u);
}

// ---------------------------------------------------------------------------
// Kernel 0: MERGED prep. g<5120: bFlat[kt][kg][c][j] fp16 image of
// [beta_u|beta_z] (validated r11-r14). g in [5120,5120+BB]: segment
// boundary binary search (validated r2-r14).
// ---------------------------------------------------------------------------
__global__ void prep_k(const float* __restrict__ bu, const float* __restrict__ bz,
                       unsigned short* __restrict__ bFlat,
                       const int* __restrict__ seg, int* __restrict__ segstart) {
  int g = blockIdx.x * 256 + threadIdx.x;
  if (g < 5120) {
    int kt  = g / 640;
    int rem = g - kt * 640;
    int kg  = rem / 160;
    int c   = rem - kg * 160;
    unsigned short* dst = bFlat + (size_t)g * 8;
    int kbase = kt * 32 + kg * 8;
#pragma unroll
    for (int j = 0; j < 8; ++j) {
      int k = kbase + j;
      float v = (c < PS) ? bu[k * PS + c] : bz[k * PS + (c - PS)];
      dst[j] = f16b(v);
    }
  } else if (g <= 5120 + BB) {
    int b = g - 5120;
    if (b == BB) { segstart[BB] = NN; return; }
    int lo = 0, hi = NN;
    while (lo < hi) {
      int mid = (lo + hi) >> 1;
      if (seg[mid] < b) lo = mid + 1; else hi = mid;
    }
    segstart[b] = lo;
  }
}

// ---------------------------------------------------------------------------
// Kernel 1: FUSED fp16 MFMA GEMM (16x160x256 per 1-WAVE block) + pool.
// ZERO barriers, zero staging LDS, zero inter-wave coupling:
//  1. bulk-issue all 16 x float4 loads (ONE amortized HBM stall - r12 lesson)
//     + B k-tile 0 from L2 bFlat.
//  2. cvt f32->f16 into xh[8] f16x8 frags (frees the 64 f32 VGPRs ->
//     K-loop live set ~120 <= 128 -> 16 independent waves/CU).
//  3. K-loop: 8 x {10 MFMA (all 160 cols), reload B (depth-1, L2)}.
//     Pure registers. Latency hidden by 16 unsynced waves/CU (TLP).
//  4. res tile -> 7.7KB LDS, lgkmcnt(0) (same-wave, no barrier), pool,
//     partial write.
// MFMA 16x16x32_f16: A row=lane&15, k=8*(lane>>4)+j; D col=lane&15,
// row=(lane>>4)*4+reg  [verified r3-r14].
// ---------------------------------------------------------------------------
__global__ __launch_bounds__(64, 4) void fused_k(
    const float* __restrict__ x, const unsigned short* __restrict__ bFlat,
    const int* __restrict__ seg, const int* __restrict__ segstart,
    float* __restrict__ pm, float* __restrict__ pse, float* __restrict__ pst) {
  __shared__ __align__(16) char smem[7680];   // res_u 5120 + res_v 2560
  const int lane = threadIdx.x;
  const int rs   = blockIdx.x * RT;
  const int lrow = lane & 15;
  const int lk16 = lane >> 4;

  const float* xA = x + (size_t)(rs + lrow) * QQ + lk16 * 8;
  const unsigned short* bA = bFlat + ((size_t)lk16 * 160 + lrow) * 8;

  // ---- 1. bulk-issue A (16 float4) + B tile 0 ----
  float4 xs[16];
#pragma unroll
  for (int t = 0; t < NITER; ++t) {
    xs[2 * t]     = *reinterpret_cast<const float4*>(xA + t * 32);
    xs[2 * t + 1] = *reinterpret_cast<const float4*>(xA + t * 32 + 4);
  }
  f16x8 br[10];
#pragma unroll
  for (int n = 0; n < 10; ++n)
    br[n] = *reinterpret_cast<const f16x8*>(bA + n * 128);

  // ---- 2. cvt to fp16 frags (frees xs) ----
  f16x8 xh[8];
#pragma unroll
  for (int t = 0; t < NITER; ++t) {
    float4 v0 = xs[2 * t], v1 = xs[2 * t + 1];
    xh[t][0] = (_Float16)v0.x; xh[t][1] = (_Float16)v0.y;
    xh[t][2] = (_Float16)v0.z; xh[t][3] = (_Float16)v0.w;
    xh[t][4] = (_Float16)v1.x; xh[t][5] = (_Float16)v1.y;
    xh[t][6] = (_Float16)v1.z; xh[t][7] = (_Float16)v1.w;
  }

  f32x4 acc[10];
#pragma unroll
  for (int n = 0; n < 10; ++n) acc[n] = (f32x4){0.f, 0.f, 0.f, 0.f};

  // ---- 3. pure-register K-loop ----
#pragma unroll
  for (int t = 0; t < NITER; ++t) {
    __builtin_amdgcn_s_setprio(1);
#pragma unroll
    for (int n = 0; n < 10; ++n)
      acc[n] = __builtin_amdgcn_mfma_f32_16x16x32_f16(xh[t], br[n], acc[n], 0, 0, 0);
    __builtin_amdgcn_s_setprio(0);
    if (t < NITER - 1) {
#pragma unroll
      for (int n = 0; n < 10; ++n)
        br[n] = *reinterpret_cast<const f16x8*>(bA + (t + 1) * 5120 + n * 128);
    }
  }

  // ---- 4. res tile -> LDS; same-wave pool (no barrier) ----
  float* res_u          = reinterpret_cast<float*>(smem);                 // 5120
  unsigned short* res_v = reinterpret_cast<unsigned short*>(smem + 5120); // 2560
#pragma unroll
  for (int n = 0; n < 10; ++n)
#pragma unroll
    for (int r = 0; r < 4; ++r) {
      int row = lk16 * 4 + r;
      if (n < 5) res_u[row * 80 + n * 16 + lrow] = acc[n][r];
      else       res_v[row * 80 + (n - 5) * 16 + lrow] = f16b(acc[n][r]);
    }
  asm volatile("s_waitcnt lgkmcnt(0)" ::: "memory");
  __builtin_amdgcn_sched_barrier(0);

  int b0 = seg[rs];
  int b1 = seg[rs + RT - 1];
  int nu = (b1 - b0 + 1) * PS;
  for (int u = lane; u < nu; u += 64) {
    int bag = b0 + u / PS;
    int c   = u % PS;
    int sb  = segstart[bag];
    int lo  = max(sb, rs) - rs;
    int hi  = min(segstart[bag + 1], rs + RT) - rs;
    float m_ = -3.4e38f, se = 0.f, st = 0.f;
    for (int r = lo; r < hi; ++r) {
      float v  = res_u[r * 80 + c];
      float tv = f16tof(res_v[r * 80 + c]);
      float nm = fmaxf(m_, v);
      float sc = __expf(m_ - nm);
      float ee = __expf(v - nm);
      se = se * sc + ee;
      st = st * sc + ee * tv;
      m_ = nm;
    }
    int slot = blockIdx.x - (sb >> 4);
    size_t p = ((size_t)bag * NSLOT + slot) * PS + c;
    pm[p] = m_; pse[p] = se; pst[p] = st;
  }
}

// ---------------------------------------------------------------------------
// Kernel 2: MERGED combine + finalize (r13-validated; NSLOT=10, >>4 shift).
// One block per column c (80 x 256). Slot-merge -> zsh[4096] + moments ->
// stats -> scaled write.
// ---------------------------------------------------------------------------
__device__ inline float wave_sum(float v) {
#pragma unroll
  for (int o = 32; o > 0; o >>= 1) v += __shfl_down(v, o, 64);
  return v;
}

__global__ __launch_bounds__(256) void combfin_k(
    const int* __restrict__ segstart,
    const float* __restrict__ pm, const float* __restrict__ pse,
    const float* __restrict__ pst, const float* __restrict__ bz,
    float* __restrict__ out) {
  const int c = blockIdx.x;   // 0..79
  const int t = threadIdx.x;  // 0..255 (== Q rows for bz reduction)
  __shared__ float zsh[BB];   // 16 KB

  float bvz = bz[t * PS + c];
  float bsq = bvz * bvz;

  float s = 0.f, ss = 0.f;
  for (int b = t; b < BB; b += 256) {
    int sb = segstart[b], eb = segstart[b + 1];
    float z = 0.f;
    if (eb > sb) {
      int ns = ((eb - 1) >> 4) - (sb >> 4) + 1;
      ns = min(ns, NSLOT);
      float m = -3.4e38f, se = 0.f, st = 0.f;
      for (int sl = 0; sl < ns; ++sl) {
        size_t p = ((size_t)b * NSLOT + sl) * PS + c;
        float m2 = pm[p], se2 = pse[p], st2 = pst[p];
        float nm = fmaxf(m, m2);
        float s1 = __expf(m - nm);
        float s2 = __expf(m2 - nm);
        se = se * s1 + se2 * s2;
        st = st * s1 + st2 * s2;
        m = nm;
      }
      z = st / se;
    }
    zsh[b] = z;
    s += z;
    ss += z * z;
  }

  __shared__ float w0[4], w1[4], w2[4];
  float a0 = wave_sum(bsq);
  float a1 = wave_sum(s);
  float a2 = wave_sum(ss);
  int wid = t >> 6, lane = t & 63;
  if (lane == 0) { w0[wid] = a0; w1[wid] = a1; w2[wid] = a2; }
  __syncthreads();

  __shared__ float sh[3];
  if (t == 0) {
    float B0 = w0[0] + w0[1] + w0[2] + w0[3];
    float S1 = w1[0] + w1[1] + w1[2] + w1[3];
    float S2 = w2[0] + w2[1] + w2[2] + w2[3];
    float bval = sqrtf(B0 / (float)QQ);
    float mean = S1 / (float)BB;
    float var = (S2 - (float)BB * mean * mean) / (float)(BB - 1);
    float sd = sqrtf(fmaxf(var, 0.f));
    if (!(sd > 0.f) || sd != sd) sd = 1.f;
    sh[0] = bval; sh[1] = mean; sh[2] = sd;
  }
  __syncthreads();
  float bval = sh[0], mean = sh[1], sd = sh[2];
  for (int b = t; b < BB; b += 256) {
    out[b * PS + c] = bval * (zsh[b] - mean) / sd;
  }
}

// ---------------------------------------------------------------------------
extern "C" void kernel_launch(void* const* d_in, const int* in_sizes, int n_in,
                              void* d_out, int out_size, void* d_ws, size_t ws_size,
                              hipStream_t stream) {
  const float* x   = (const float*)d_in[0];
  const float* bu  = (const float*)d_in[1];
  const float* bz  = (const float*)d_in[2];
  const int*   seg = (const int*)d_in[3];   // harness narrows int64 -> int32
  float* out = (float*)d_out;

  // workspace layout (bytes):
  //   [0,     16640)  segstart (4097 ints, padded)
  //   [16640, 98560)  bFlat: 8*4*160*8 fp16 = 81920
  //   [98560, ...)    pm / pse / pst: BB*NSLOT*PS floats each (13.1 MB each)
  char* ws = (char*)d_ws;
  int* segstart         = (int*)ws;
  unsigned short* bFlat = (unsigned short*)(ws + 16640);
  size_t pn  = (size_t)BB * NSLOT * PS;
  float* pm  = (float*)(ws + 98560);
  float* pse = pm + pn;
  float* pst = pse + pn;

  prep_k<<<(5120 + BB + 1 + 255) / 256, 256, 0, stream>>>(bu, bz, bFlat, seg, segstart);
  fused_k<<<NN / RT, 64, 0, stream>>>(x, bFlat, seg, segstart, pm, pse, pst);
  combfin_k<<<PS, 256, 0, stream>>>(segstart, pm, pse, pst, bz, out);
}

// Round 16
// 144.256 us; speedup vs baseline: 1.1747x; 1.1747x over previous
//
#include <hip/hip_runtime.h>
#include <hip/hip_bf16.h>
#include <math.h>

#define NN 262144
#define QQ 256
#define PS 80
#define BB 4096
#define NSLOT 4
#define RT 64             // rows per strip
#define NITER 8           // K tiles of 32
#define SMEM_BYTES 65536  // A-f32 async stage [kt 8][w8 8][row 8][chunk 8][16B]; res union 30720

typedef _Float16 f16x8 __attribute__((ext_vector_type(8)));
typedef float f32x4  __attribute__((ext_vector_type(4)));
typedef const __attribute__((address_space(1))) unsigned int g_u32;
typedef __attribute__((address_space(3))) unsigned int l_u32;

__device__ inline unsigned short f16b(float f) {
  return __builtin_bit_cast(unsigned short, (_Float16)f);
}
__device__ inline float f16tof(unsigned short u) {
  return (float)__builtin_bit_cast(_Float16, u);
}

// ---------------------------------------------------------------------------
// Kernel 0: MERGED prep (validated r14). g<5120: bFlat[kt][kg][c][j] fp16
// image of [beta_u|beta_z]. g in [5120,5120+BB]: segment boundary search.
// ---------------------------------------------------------------------------
__global__ void prep_k(const float* __restrict__ bu, const float* __restrict__ bz,
                       unsigned short* __restrict__ bFlat,
                       const int* __restrict__ seg, int* __restrict__ segstart) {
  int g = blockIdx.x * 256 + threadIdx.x;
  if (g < 5120) {
    int kt  = g / 640;
    int rem = g - kt * 640;
    int kg  = rem / 160;
    int c   = rem - kg * 160;
    unsigned short* dst = bFlat + (size_t)g * 8;
    int kbase = kt * 32 + kg * 8;
#pragma unroll
    for (int j = 0; j < 8; ++j) {
      int k = kbase + j;
      float v = (c < PS) ? bu[k * PS + c] : bz[k * PS + (c - PS)];
      dst[j] = f16b(v);
    }
  } else if (g <= 5120 + BB) {
    int b = g - 5120;
    if (b == BB) { segstart[BB] = NN; return; }
    int lo = 0, hi = NN;
    while (lo < hi) {
      int mid = (lo + hi) >> 1;
      if (seg[mid] < b) lo = mid + 1; else hi = mid;
    }
    segstart[b] = lo;
  }
}

// ---------------------------------------------------------------------------
// Kernel 1: FUSED fp16 MFMA GEMM (64x160x256) + segmented softmax-pool.
// r16: ZERO-REGISTER full-strip async A-prefetch.
//  - All 16 global_load_lds per wave (whole 64x256 f32 strip, 128KB/CU in
//    flight at cycle 0 -> HBM saturated) issued kt-ascending; B (L2 bFlat)
//    global->reg depth-2 issued after (order pinned by memory-clobber fences).
//  - Per k-tile: s_waitcnt vmcnt(24+3kt) (exact: 2(7-kt) A-ops + 10+5kt B-ops
//    younger than A-kt) + raw s_barrier -> tiles kt+1.. keep streaming under
//    MFMA of tile kt. No vmcnt(0) until the epilogue.
//  - A stored as f32; cvt f32->f16 at fragment read (~25 VALU/tile).
//  - LDS image per inst: [kt][w8=row>>3][row&7][stored-chunk s][16B] with
//    s = g ^ (row&7) via pre-swizzled per-lane SOURCE (m173 pattern):
//    lane L: row = w8*8 + (L>>3), g = (L&7) ^ (L>>3). Per-inst coalescing
//    perfect (8 rows x full 128B line); frag-read banks = s*4+w, s spans 8
//    values over row&7 -> 2-way max (free).
// MFMA 16x16x32_f16: A row=lane&15, k=8*(lane>>4)+j; D col=lane&15,
// row=(lane>>4)*4+reg  [verified r3-r15].
// ---------------------------------------------------------------------------
__global__ __launch_bounds__(256, 2) void fused_k(
    const float* __restrict__ x, const unsigned short* __restrict__ bFlat,
    const int* __restrict__ seg, const int* __restrict__ segstart,
    float* __restrict__ pm, float* __restrict__ pse, float* __restrict__ pst) {
  __shared__ __align__(16) char smem[SMEM_BYTES];
  const int tid  = threadIdx.x;
  const int lane = tid & 63;
  const int wid  = tid >> 6;
  const int rs   = blockIdx.x * RT;

  const int wr   = (wid & 1) * 32;   // wave row offset
  const int cw   = wid >> 1;         // 0 -> u cols, 1 -> tz cols
  const int lrow = lane & 15;
  const int lk16 = lane >> 4;

  // ---- A async stage: 2 inst per kt per wave (w8 = 2*wid, 2*wid+1) ----
  const int l8 = lane >> 3;          // row-in-group 0..7
  const int g8 = (lane & 7) ^ l8;    // pre-swizzled source chunk
  const int w8a = wid * 2, w8b = wid * 2 + 1;
  const float* srcA = x + (size_t)(rs + w8a * 8 + l8) * QQ + g8 * 4;
  const float* srcB = x + (size_t)(rs + w8b * 8 + l8) * QQ + g8 * 4;
  char* dstA = smem + w8a * 1024;    // uniform; HW adds lane*16
  char* dstB = smem + w8b * 1024;
#pragma unroll
  for (int kt = 0; kt < NITER; ++kt) {
    __builtin_amdgcn_global_load_lds((g_u32*)(srcA + kt * 32),
                                     (l_u32*)(dstA + kt * 8192), 16, 0, 0);
    __builtin_amdgcn_global_load_lds((g_u32*)(srcB + kt * 32),
                                     (l_u32*)(dstB + kt * 8192), 16, 0, 0);
  }
  asm volatile("" ::: "memory");     // pin: A gloads precede B loads in queue

  // ---- B prologue (L2-resident bFlat, depth-2) ----
  const unsigned short* bA = bFlat + ((size_t)lk16 * 160 + cw * 80 + lrow) * 8;
  f16x8 br[2][5];
#define LOADB(s_, t_) do {                                                    \
    _Pragma("unroll")                                                         \
    for (int n_ = 0; n_ < 5; ++n_)                                            \
      br[s_][n_] = *reinterpret_cast<const f16x8*>(bA + (t_) * 5120 + n_ * 128); \
  } while (0)
  LOADB(0, 0);
  LOADB(1, 1);
  asm volatile("" ::: "memory");     // pin B prologue before loop body

  f32x4 acc[2][5];
#pragma unroll
  for (int m = 0; m < 2; ++m)
#pragma unroll
    for (int n = 0; n < 5; ++n) acc[m][n] = (f32x4){0.f, 0.f, 0.f, 0.f};

  // queue per wave: A kt0..kt7 (2 each, pos 1-16) | B0 17-21 | B1 22-26 |
  // +5 reload per finished iter. A-kt done <=> outstanding <= 24+3kt.
#define KITER(t_, v_) do {                                                    \
    asm volatile("s_waitcnt vmcnt(" #v_ ")" ::: "memory");                    \
    __builtin_amdgcn_s_barrier();                                             \
    const int s_ = (t_) & 1;                                                  \
    f16x8 af[2];                                                              \
    _Pragma("unroll")                                                         \
    for (int m_ = 0; m_ < 2; ++m_) {                                          \
      int r_ = wr + m_ * 16 + lrow;                                           \
      int s0_ = (2 * lk16) ^ (r_ & 7);                                        \
      const char* base_ = smem + (t_) * 8192 + (r_ >> 3) * 1024 + (r_ & 7) * 128; \
      f32x4 c0 = *reinterpret_cast<const f32x4*>(base_ + s0_ * 16);           \
      f32x4 c1 = *reinterpret_cast<const f32x4*>(base_ + (s0_ ^ 1) * 16);     \
      af[m_][0] = (_Float16)c0[0]; af[m_][1] = (_Float16)c0[1];               \
      af[m_][2] = (_Float16)c0[2]; af[m_][3] = (_Float16)c0[3];               \
      af[m_][4] = (_Float16)c1[0]; af[m_][5] = (_Float16)c1[1];               \
      af[m_][6] = (_Float16)c1[2]; af[m_][7] = (_Float16)c1[3];               \
    }                                                                         \
    __builtin_amdgcn_s_setprio(1);                                            \
    _Pragma("unroll")                                                         \
    for (int n_ = 0; n_ < 5; ++n_) {                                          \
      acc[0][n_] = __builtin_amdgcn_mfma_f32_16x16x32_f16(af[0], br[s_][n_], acc[0][n_], 0, 0, 0); \
      acc[1][n_] = __builtin_amdgcn_mfma_f32_16x16x32_f16(af[1], br[s_][n_], acc[1][n_], 0, 0, 0); \
    }                                                                         \
    __builtin_amdgcn_s_setprio(0);                                            \
    if ((t_) < NITER - 2) LOADB(s_, (t_) + 2);                                \
  } while (0)

  KITER(0, 24); KITER(1, 27); KITER(2, 30); KITER(3, 33);
  KITER(4, 36); KITER(5, 39); KITER(6, 42); KITER(7, 45);
#undef KITER
#undef LOADB

  // ---- result tile -> LDS (res union over staging), pool ----
  __syncthreads();   // full drain; staging area now dead
  float* res_u          = reinterpret_cast<float*>(smem);                  // 20480
  unsigned short* res_v = reinterpret_cast<unsigned short*>(smem + 20480); // 10240
#pragma unroll
  for (int m = 0; m < 2; ++m)
#pragma unroll
    for (int n = 0; n < 5; ++n)
#pragma unroll
      for (int rr = 0; rr < 4; ++rr) {
        int row = wr + m * 16 + lk16 * 4 + rr;
        int col = n * 16 + lrow;
        if (cw == 0) res_u[row * 80 + col] = acc[m][n][rr];
        else         res_v[row * 80 + col] = f16b(acc[m][n][rr]);
      }
  __syncthreads();

  // segmented online softmax-pool over this 64-row strip
  int b0 = seg[rs];
  int b1 = seg[rs + RT - 1];
  int nu = (b1 - b0 + 1) * PS;
  for (int u = tid; u < nu; u += 256) {
    int bag = b0 + u / PS;
    int c   = u % PS;
    int sb  = segstart[bag];
    int lo  = max(sb, rs) - rs;
    int hi  = min(segstart[bag + 1], rs + RT) - rs;
    float m_ = -3.4e38f, se = 0.f, st = 0.f;
    for (int r = lo; r < hi; ++r) {
      float v  = res_u[r * 80 + c];
      float tv = f16tof(res_v[r * 80 + c]);
      float nm = fmaxf(m_, v);
      float sc = __expf(m_ - nm);
      float ee = __expf(v - nm);
      se = se * sc + ee;
      st = st * sc + ee * tv;
      m_ = nm;
    }
    int slot = blockIdx.x - (sb >> 6);
    size_t p = ((size_t)bag * NSLOT + slot) * PS + c;
    pm[p] = m_; pse[p] = se; pst[p] = st;
  }
}

// ---------------------------------------------------------------------------
// Kernel 2: MERGED combine + finalize (validated r13/r14). One block per
// column c (80 x 256). Slot-merge -> zsh[4096] + moments -> stats -> write.
// ---------------------------------------------------------------------------
__device__ inline float wave_sum(float v) {
#pragma unroll
  for (int o = 32; o > 0; o >>= 1) v += __shfl_down(v, o, 64);
  return v;
}

__global__ __launch_bounds__(256) void combfin_k(
    const int* __restrict__ segstart,
    const float* __restrict__ pm, const float* __restrict__ pse,
    const float* __restrict__ pst, const float* __restrict__ bz,
    float* __restrict__ out) {
  const int c = blockIdx.x;   // 0..79
  const int t = threadIdx.x;  // 0..255 (== Q rows for bz reduction)
  __shared__ float zsh[BB];   // 16 KB

  float bvz = bz[t * PS + c];
  float bsq = bvz * bvz;

  float s = 0.f, ss = 0.f;
  for (int b = t; b < BB; b += 256) {
    int sb = segstart[b], eb = segstart[b + 1];
    float z = 0.f;
    if (eb > sb) {
      int ns = ((eb - 1) >> 6) - (sb >> 6) + 1;
      ns = min(ns, NSLOT);
      float m = -3.4e38f, se = 0.f, st = 0.f;
      for (int sl = 0; sl < ns; ++sl) {
        size_t p = ((size_t)b * NSLOT + sl) * PS + c;
        float m2 = pm[p], se2 = pse[p], st2 = pst[p];
        float nm = fmaxf(m, m2);
        float s1 = __expf(m - nm);
        float s2 = __expf(m2 - nm);
        se = se * s1 + se2 * s2;
        st = st * s1 + st2 * s2;
        m = nm;
      }
      z = st / se;
    }
    zsh[b] = z;
    s += z;
    ss += z * z;
  }

  __shared__ float w0[4], w1[4], w2[4];
  float a0 = wave_sum(bsq);
  float a1 = wave_sum(s);
  float a2 = wave_sum(ss);
  int wid = t >> 6, lane = t & 63;
  if (lane == 0) { w0[wid] = a0; w1[wid] = a1; w2[wid] = a2; }
  __syncthreads();

  __shared__ float sh[3];
  if (t == 0) {
    float B0 = w0[0] + w0[1] + w0[2] + w0[3];
    float S1 = w1[0] + w1[1] + w1[2] + w1[3];
    float S2 = w2[0] + w2[1] + w2[2] + w2[3];
    float bval = sqrtf(B0 / (float)QQ);
    float mean = S1 / (float)BB;
    float var = (S2 - (float)BB * mean * mean) / (float)(BB - 1);
    float sd = sqrtf(fmaxf(var, 0.f));
    if (!(sd > 0.f) || sd != sd) sd = 1.f;
    sh[0] = bval; sh[1] = mean; sh[2] = sd;
  }
  __syncthreads();
  float bval = sh[0], mean = sh[1], sd = sh[2];
  for (int b = t; b < BB; b += 256) {
    out[b * PS + c] = bval * (zsh[b] - mean) / sd;
  }
}

// ---------------------------------------------------------------------------
extern "C" void kernel_launch(void* const* d_in, const int* in_sizes, int n_in,
                              void* d_out, int out_size, void* d_ws, size_t ws_size,
                              hipStream_t stream) {
  const float* x   = (const float*)d_in[0];
  const float* bu  = (const float*)d_in[1];
  const float* bz  = (const float*)d_in[2];
  const int*   seg = (const int*)d_in[3];   // harness narrows int64 -> int32
  float* out = (float*)d_out;

  // workspace layout (bytes):
  //   [0,     16640)  segstart (4097 ints, padded)
  //   [16640, 98560)  bFlat: 8*4*160*8 fp16 = 81920
  //   [98560, ...)    pm / pse / pst: BB*NSLOT*PS floats each
  char* ws = (char*)d_ws;
  int* segstart         = (int*)ws;
  unsigned short* bFlat = (unsigned short*)(ws + 16640);
  size_t pn  = (size_t)BB * NSLOT * PS;
  float* pm  = (float*)(ws + 98560);
  float* pse = pm + pn;
  float* pst = pse + pn;

  prep_k<<<(5120 + BB + 1 + 255) / 256, 256, 0, stream>>>(bu, bz, bFlat, seg, segstart);
  fused_k<<<NN / RT, 256, 0, stream>>>(x, bFlat, seg, segstart, pm, pse, pst);
  combfin_k<<<PS, 256, 0, stream>>>(segstart, pm, pse, pst, bz, out);
}

// Round 17
// 133.616 us; speedup vs baseline: 1.2682x; 1.0796x over previous
//
#include <hip/hip_runtime.h>
#include <hip/hip_bf16.h>
#include <math.h>

#define NN 262144
#define QQ 256
#define PS 80
#define BB 4096
#define NSLOT 6           // bag spans <= 6 32-row strips (max bag ~100 rows @ +5sigma)
#define RT 32             // rows per strip
#define NITER 8           // K tiles of 32
#define SMEM_BYTES 16384  // A fp16 [8 kt][4 kg][32 row^swz][16B]; res union 15360

typedef _Float16 f16x8 __attribute__((ext_vector_type(8)));
typedef float f32x4  __attribute__((ext_vector_type(4)));

__device__ inline unsigned short f16b(float f) {
  return __builtin_bit_cast(unsigned short, (_Float16)f);
}
__device__ inline float f16tof(unsigned short u) {
  return (float)__builtin_bit_cast(_Float16, u);
}

// ---------------------------------------------------------------------------
// Kernel 0: MERGED prep (validated r14-r16). g<5120: bFlat[kt][kg][c][j] fp16
// image of [beta_u|beta_z]. g in [5120,5120+BB]: segment boundary search.
// ---------------------------------------------------------------------------
__global__ void prep_k(const float* __restrict__ bu, const float* __restrict__ bz,
                       unsigned short* __restrict__ bFlat,
                       const int* __restrict__ seg, int* __restrict__ segstart) {
  int g = blockIdx.x * 256 + threadIdx.x;
  if (g < 5120) {
    int kt  = g / 640;
    int rem = g - kt * 640;
    int kg  = rem / 160;
    int c   = rem - kg * 160;
    unsigned short* dst = bFlat + (size_t)g * 8;
    int kbase = kt * 32 + kg * 8;
#pragma unroll
    for (int j = 0; j < 8; ++j) {
      int k = kbase + j;
      float v = (c < PS) ? bu[k * PS + c] : bz[k * PS + (c - PS)];
      dst[j] = f16b(v);
    }
  } else if (g <= 5120 + BB) {
    int b = g - 5120;
    if (b == BB) { segstart[BB] = NN; return; }
    int lo = 0, hi = NN;
    while (lo < hi) {
      int mid = (lo + hi) >> 1;
      if (seg[mid] < b) lo = mid + 1; else hi = mid;
    }
    segstart[b] = lo;
  }
}

// ---------------------------------------------------------------------------
// Kernel 1: FUSED fp16 MFMA GEMM (32x160x256 per block) + pool.
// r17 = r12 champion structure at RT=32 for 6 blocks/CU:
//  - bulk-issue 8 x-float4/thread (one amortized HBM stall), cvt f32->f16,
//    8 uint2 ds_writes, ONE barrier.
//  - barrier-free unrolled K-loop: {1 ds_read_b128 A-frag, 5 MFMA,
//    B depth-1 reload from L2 bFlat}.
//  - register budget engineered for launch_bounds(256,6) (<=85 VGPR):
//    staging transient ~45 (8 float4 + addr), K-loop ~65 (acc 20 + br 20 +
//    af 4 + addr) -> no spill (the r13/r15 failure mode).
//  - LDS A [kt 8][kg 4][row^(kg<<2)][16B] = 16 KB; res union 15.4 KB.
// MFMA 16x16x32_f16: A row=lane&15, k=8*(lane>>4)+j; D col=lane&15,
// row=(lane>>4)*4+reg  [verified r3-r16].
// ---------------------------------------------------------------------------
__global__ __launch_bounds__(256, 6) void fused_k(
    const float* __restrict__ x, const unsigned short* __restrict__ bFlat,
    const int* __restrict__ seg, const int* __restrict__ segstart,
    float* __restrict__ pm, float* __restrict__ pse, float* __restrict__ pst) {
  __shared__ __align__(16) char smem[SMEM_BYTES];
  const int tid  = threadIdx.x;
  const int lane = tid & 63;
  const int wid  = tid >> 6;
  const int rs   = blockIdx.x * RT;

  const int wr   = (wid & 1) * 16;   // wave row offset (0,16)
  const int cw   = wid >> 1;         // 0 -> u cols, 1 -> tz cols
  const int lrow = lane & 15;
  const int lk16 = lane >> 4;

  // ---------- staging: 32 rows x 256 k, 8 float4 per thread ----------
  {
    const int ra = tid >> 3;         // 0..31
    const int q  = tid & 7;          // float4 slot within 32-k window? no:
                                     // one float4 PER k-tile at k=4q
    const float* xp = x + (size_t)(rs + ra) * QQ + q * 4;
    float4 xs[8];
#pragma unroll
    for (int kt = 0; kt < NITER; ++kt)
      xs[kt] = *reinterpret_cast<const float4*>(xp + kt * 32);
    const int kg  = q >> 1;
    const int sub = q & 1;
    char* adst = smem + kg * 512 + ((ra ^ (kg << 2)) * 16) + sub * 8;
#pragma unroll
    for (int kt = 0; kt < NITER; ++kt) {
      float4 v = xs[kt];
      unsigned short a0 = f16b(v.x), a1 = f16b(v.y), a2 = f16b(v.z), a3 = f16b(v.w);
      uint2 w = make_uint2((unsigned)a0 | ((unsigned)a1 << 16),
                           (unsigned)a2 | ((unsigned)a3 << 16));
      *reinterpret_cast<uint2*>(adst + kt * 2048) = w;
    }
  }
  __syncthreads();

  // ---------- barrier-free K-loop ----------
  const unsigned short* bA = bFlat + ((size_t)lk16 * 160 + cw * 80 + lrow) * 8;
  const int aoff = lk16 * 512 + (((wr + lrow) ^ (lk16 << 2)) * 16);

  f16x8 br[5];
#define LOADB(t_) do {                                                        \
    _Pragma("unroll")                                                         \
    for (int n_ = 0; n_ < 5; ++n_)                                            \
      br[n_] = *reinterpret_cast<const f16x8*>(bA + (t_) * 5120 + n_ * 128);  \
  } while (0)
  LOADB(0);

  f32x4 acc[5];
#pragma unroll
  for (int n = 0; n < 5; ++n) acc[n] = (f32x4){0.f, 0.f, 0.f, 0.f};

#pragma unroll
  for (int t = 0; t < NITER; ++t) {
    f16x8 af = *reinterpret_cast<const f16x8*>(smem + t * 2048 + aoff);
    __builtin_amdgcn_s_setprio(1);
#pragma unroll
    for (int n = 0; n < 5; ++n)
      acc[n] = __builtin_amdgcn_mfma_f32_16x16x32_f16(af, br[n], acc[n], 0, 0, 0);
    __builtin_amdgcn_s_setprio(0);
    if (t < NITER - 1) LOADB(t + 1);
  }
#undef LOADB

  // ---------- result tile -> LDS (res union), pool ----------
  __syncthreads();   // all A ds_reads done before staging area is overwritten
  float* res_u          = reinterpret_cast<float*>(smem);                  // 10240
  unsigned short* res_v = reinterpret_cast<unsigned short*>(smem + 10240); // 5120
#pragma unroll
  for (int n = 0; n < 5; ++n)
#pragma unroll
    for (int rr = 0; rr < 4; ++rr) {
      int row = wr + lk16 * 4 + rr;
      int col = n * 16 + lrow;
      if (cw == 0) res_u[row * 80 + col] = acc[n][rr];
      else         res_v[row * 80 + col] = f16b(acc[n][rr]);
    }
  __syncthreads();

  // segmented online softmax-pool over this 32-row strip
  int b0 = seg[rs];
  int b1 = seg[rs + RT - 1];
  int nu = (b1 - b0 + 1) * PS;
  for (int u = tid; u < nu; u += 256) {
    int bag = b0 + u / PS;
    int c   = u % PS;
    int sb  = segstart[bag];
    int lo  = max(sb, rs) - rs;
    int hi  = min(segstart[bag + 1], rs + RT) - rs;
    float m_ = -3.4e38f, se = 0.f, st = 0.f;
    for (int r = lo; r < hi; ++r) {
      float v  = res_u[r * 80 + c];
      float tv = f16tof(res_v[r * 80 + c]);
      float nm = fmaxf(m_, v);
      float sc = __expf(m_ - nm);
      float ee = __expf(v - nm);
      se = se * sc + ee;
      st = st * sc + ee * tv;
      m_ = nm;
    }
    int slot = blockIdx.x - (sb >> 5);
    size_t p = ((size_t)bag * NSLOT + slot) * PS + c;
    pm[p] = m_; pse[p] = se; pst[p] = st;
  }
}

// ---------------------------------------------------------------------------
// Kernel 2: MERGED combine + finalize (validated r13-r16; NSLOT=6, >>5).
// One block per column c (80 x 256). Slot-merge -> zsh[4096] + moments ->
// stats -> scaled write.
// ---------------------------------------------------------------------------
__device__ inline float wave_sum(float v) {
#pragma unroll
  for (int o = 32; o > 0; o >>= 1) v += __shfl_down(v, o, 64);
  return v;
}

__global__ __launch_bounds__(256) void combfin_k(
    const int* __restrict__ segstart,
    const float* __restrict__ pm, const float* __restrict__ pse,
    const float* __restrict__ pst, const float* __restrict__ bz,
    float* __restrict__ out) {
  const int c = blockIdx.x;   // 0..79
  const int t = threadIdx.x;  // 0..255 (== Q rows for bz reduction)
  __shared__ float zsh[BB];   // 16 KB

  float bvz = bz[t * PS + c];
  float bsq = bvz * bvz;

  float s = 0.f, ss = 0.f;
  for (int b = t; b < BB; b += 256) {
    int sb = segstart[b], eb = segstart[b + 1];
    float z = 0.f;
    if (eb > sb) {
      int ns = ((eb - 1) >> 5) - (sb >> 5) + 1;
      ns = min(ns, NSLOT);
      float m = -3.4e38f, se = 0.f, st = 0.f;
      for (int sl = 0; sl < ns; ++sl) {
        size_t p = ((size_t)b * NSLOT + sl) * PS + c;
        float m2 = pm[p], se2 = pse[p], st2 = pst[p];
        float nm = fmaxf(m, m2);
        float s1 = __expf(m - nm);
        float s2 = __expf(m2 - nm);
        se = se * s1 + se2 * s2;
        st = st * s1 + st2 * s2;
        m = nm;
      }
      z = st / se;
    }
    zsh[b] = z;
    s += z;
    ss += z * z;
  }

  __shared__ float w0[4], w1[4], w2[4];
  float a0 = wave_sum(bsq);
  float a1 = wave_sum(s);
  float a2 = wave_sum(ss);
  int wid = t >> 6, lane = t & 63;
  if (lane == 0) { w0[wid] = a0; w1[wid] = a1; w2[wid] = a2; }
  __syncthreads();

  __shared__ float sh[3];
  if (t == 0) {
    float B0 = w0[0] + w0[1] + w0[2] + w0[3];
    float S1 = w1[0] + w1[1] + w1[2] + w1[3];
    float S2 = w2[0] + w2[1] + w2[2] + w2[3];
    float bval = sqrtf(B0 / (float)QQ);
    float mean = S1 / (float)BB;
    float var = (S2 - (float)BB * mean * mean) / (float)(BB - 1);
    float sd = sqrtf(fmaxf(var, 0.f));
    if (!(sd > 0.f) || sd != sd) sd = 1.f;
    sh[0] = bval; sh[1] = mean; sh[2] = sd;
  }
  __syncthreads();
  float bval = sh[0], mean = sh[1], sd = sh[2];
  for (int b = t; b < BB; b += 256) {
    out[b * PS + c] = bval * (zsh[b] - mean) / sd;
  }
}

// ---------------------------------------------------------------------------
extern "C" void kernel_launch(void* const* d_in, const int* in_sizes, int n_in,
                              void* d_out, int out_size, void* d_ws, size_t ws_size,
                              hipStream_t stream) {
  const float* x   = (const float*)d_in[0];
  const float* bu  = (const float*)d_in[1];
  const float* bz  = (const float*)d_in[2];
  const int*   seg = (const int*)d_in[3];   // harness narrows int64 -> int32
  float* out = (float*)d_out;

  // workspace layout (bytes):
  //   [0,     16640)  segstart (4097 ints, padded)
  //   [16640, 98560)  bFlat: 8*4*160*8 fp16 = 81920
  //   [98560, ...)    pm / pse / pst: BB*NSLOT*PS floats each (~7.9 MB each)
  char* ws = (char*)d_ws;
  int* segstart         = (int*)ws;
  unsigned short* bFlat = (unsigned short*)(ws + 16640);
  size_t pn  = (size_t)BB * NSLOT * PS;
  float* pm  = (float*)(ws + 98560);
  float* pse = pm + pn;
  float* pst = pse + pn;

  prep_k<<<(5120 + BB + 1 + 255) / 256, 256, 0, stream>>>(bu, bz, bFlat, seg, segstart);
  fused_k<<<NN / RT, 256, 0, stream>>>(x, bFlat, seg, segstart, pm, pse, pst);
  combfin_k<<<PS, 256, 0, stream>>>(segstart, pm, pse, pst, bz, out);
}

// Round 18
// 113.911 us; speedup vs baseline: 1.4876x; 1.1730x over previous
//
#include <hip/hip_runtime.h>
#include <hip/hip_bf16.h>
#include <math.h>

#define NN 262144
#define QQ 256
#define PS 80
#define BB 4096
#define NSLOT 4
#define RT 64             // rows per strip
#define NITER 8           // K tiles of 32
#define SMEM_BYTES 32768  // A-strip fp16 [8 kt][4 kg][64 row^swz][16B]; res union 30720

typedef _Float16 f16x8 __attribute__((ext_vector_type(8)));
typedef float f32x4  __attribute__((ext_vector_type(4)));

__device__ inline unsigned short f16b(float f) {
  return __builtin_bit_cast(unsigned short, (_Float16)f);
}
__device__ inline float f16tof(unsigned short u) {
  return (float)__builtin_bit_cast(_Float16, u);
}

// ---------------------------------------------------------------------------
// Kernel 0: MERGED prep (validated r14-r17). g<5120: bFlat[kt][kg][c][j] fp16
// image of [beta_u|beta_z] (elem k = kt*32+kg*8+j). g in [5120,5120+BB]:
// segment boundary binary search (seg sorted, int32 from harness).
// ---------------------------------------------------------------------------
__global__ void prep_k(const float* __restrict__ bu, const float* __restrict__ bz,
                       unsigned short* __restrict__ bFlat,
                       const int* __restrict__ seg, int* __restrict__ segstart) {
  int g = blockIdx.x * 256 + threadIdx.x;
  if (g < 5120) {
    int kt  = g / 640;
    int rem = g - kt * 640;
    int kg  = rem / 160;
    int c   = rem - kg * 160;
    unsigned short* dst = bFlat + (size_t)g * 8;
    int kbase = kt * 32 + kg * 8;
#pragma unroll
    for (int j = 0; j < 8; ++j) {
      int k = kbase + j;
      float v = (c < PS) ? bu[k * PS + c] : bz[k * PS + (c - PS)];
      dst[j] = f16b(v);
    }
  } else if (g <= 5120 + BB) {
    int b = g - 5120;
    if (b == BB) { segstart[BB] = NN; return; }
    int lo = 0, hi = NN;
    while (lo < hi) {
      int mid = (lo + hi) >> 1;
      if (seg[mid] < b) lo = mid + 1; else hi = mid;
    }
    segstart[b] = lo;
  }
}

// ---------------------------------------------------------------------------
// Kernel 1: FUSED fp16 MFMA GEMM (64x160x256) + segmented softmax-pool.
// VERBATIM r12 champion (101.3 us total):
// Phase 1 (staging): ALL 16 x-float4 loads issued up front per thread
//   (64KB/block in flight -> HBM streaming), cvt f32->fp16, 8 uint4
//   ds_writes into [kt][kg][row^(kg<<2)][16B] (conflict-free). ONE barrier.
// Phase 2 (K-loop, NO barriers): 8 unrolled iters of
//   {2 ds_read_b128 A-frags, 10 MFMA}; B global->reg from L2-resident bFlat
//   (depth-2 slots, each slot reloaded AFTER its MFMA cluster).
// Phase 3: barrier, result->LDS (res union), barrier, in-LDS pool.
// Evidence r9-r17: every intra-block pipelining/coupling variant regresses
// (dbuf 105, vmcnt-counted 106, all-reg 138, split-half 119, quarter 123,
// 1-wave 169, async-chain 144, RT=32 134). This minimal-sync form wins.
// MFMA 16x16x32_f16: A row=lane&15, k=8*(lane>>4)+j; D col=lane&15,
// row=(lane>>4)*4+reg  [verified r3-r17].
// ---------------------------------------------------------------------------
__global__ __launch_bounds__(256, 4) void fused_k(
    const float* __restrict__ x, const unsigned short* __restrict__ bFlat,
    const int* __restrict__ seg, const int* __restrict__ segstart,
    float* __restrict__ pm, float* __restrict__ pse, float* __restrict__ pst) {
  __shared__ __align__(16) char smem[SMEM_BYTES];
  const int tid  = threadIdx.x;
  const int lane = tid & 63;
  const int wid  = tid >> 6;
  const int rs   = blockIdx.x * RT;

  const int wr   = (wid & 1) * 32;   // wave row offset
  const int cw   = wid >> 1;         // 0 -> u cols, 1 -> tz cols
  const int lrow = lane & 15;
  const int lk16 = lane >> 4;

  // ---------- Phase 1: stage whole x-strip (64 rows x 256 k) as fp16 ----------
  {
    const int ra = tid >> 2;         // 0..63
    const int kg = tid & 3;          // 0..3
    const float* xp = x + (size_t)(rs + ra) * QQ + kg * 8;
    float4 xs[16];
#pragma unroll
    for (int kt = 0; kt < NITER; ++kt) {
      xs[2 * kt]     = *reinterpret_cast<const float4*>(xp + kt * 32);
      xs[2 * kt + 1] = *reinterpret_cast<const float4*>(xp + kt * 32 + 4);
    }
    char* dst = smem + kg * 1024 + ((ra ^ (kg << 2)) * 16);
#pragma unroll
    for (int kt = 0; kt < NITER; ++kt) {
      float4 v0 = xs[2 * kt], v1 = xs[2 * kt + 1];
      unsigned short a0 = f16b(v0.x), a1 = f16b(v0.y), a2 = f16b(v0.z), a3 = f16b(v0.w);
      unsigned short a4 = f16b(v1.x), a5 = f16b(v1.y), a6 = f16b(v1.z), a7 = f16b(v1.w);
      uint4 w = make_uint4((unsigned)a0 | ((unsigned)a1 << 16),
                           (unsigned)a2 | ((unsigned)a3 << 16),
                           (unsigned)a4 | ((unsigned)a5 << 16),
                           (unsigned)a6 | ((unsigned)a7 << 16));
      *reinterpret_cast<uint4*>(dst + kt * 4096) = w;
    }
  }
  __syncthreads();

  // ---------- Phase 2: barrier-free K-loop ----------
  const unsigned short* bA = bFlat + ((size_t)lk16 * 160 + cw * 80 + lrow) * 8;
  const int aoff0 = lk16 * 1024 + (((wr + lrow)      ^ (lk16 << 2)) * 16);
  const int aoff1 = lk16 * 1024 + (((wr + 16 + lrow) ^ (lk16 << 2)) * 16);

  f16x8 br[2][5];
#define LOADB(s_, t_) do {                                                    \
    _Pragma("unroll")                                                         \
    for (int n_ = 0; n_ < 5; ++n_)                                            \
      br[s_][n_] = *reinterpret_cast<const f16x8*>(bA + (t_) * 5120 + n_ * 128); \
  } while (0)

  f32x4 acc[2][5];
#pragma unroll
  for (int m = 0; m < 2; ++m)
#pragma unroll
    for (int n = 0; n < 5; ++n) acc[m][n] = (f32x4){0.f, 0.f, 0.f, 0.f};

  LOADB(0, 0);
  LOADB(1, 1);

#pragma unroll
  for (int t = 0; t < NITER; ++t) {
    const int s = t & 1;
    f16x8 a0 = *reinterpret_cast<const f16x8*>(smem + t * 4096 + aoff0);
    f16x8 a1 = *reinterpret_cast<const f16x8*>(smem + t * 4096 + aoff1);
    __builtin_amdgcn_s_setprio(1);
#pragma unroll
    for (int n = 0; n < 5; ++n) {
      acc[0][n] = __builtin_amdgcn_mfma_f32_16x16x32_f16(a0, br[s][n], acc[0][n], 0, 0, 0);
      acc[1][n] = __builtin_amdgcn_mfma_f32_16x16x32_f16(a1, br[s][n], acc[1][n], 0, 0, 0);
    }
    __builtin_amdgcn_s_setprio(0);
    if (t < NITER - 2) LOADB(s, t + 2);   // reload slot AFTER its MFMA cluster
  }
#undef LOADB

  // ---------- Phase 3: result tile -> LDS (res union), pool ----------
  __syncthreads();   // all A ds_reads done before staging area is overwritten
  float* res_u          = reinterpret_cast<float*>(smem);                  // 20480
  unsigned short* res_v = reinterpret_cast<unsigned short*>(smem + 20480); // 10240
#pragma unroll
  for (int m = 0; m < 2; ++m)
#pragma unroll
    for (int n = 0; n < 5; ++n)
#pragma unroll
      for (int rr = 0; rr < 4; ++rr) {
        int row = wr + m * 16 + lk16 * 4 + rr;
        int col = n * 16 + lrow;
        if (cw == 0) res_u[row * 80 + col] = acc[m][n][rr];
        else         res_v[row * 80 + col] = f16b(acc[m][n][rr]);
      }
  __syncthreads();

  // segmented online softmax-pool over this 64-row strip
  int b0 = seg[rs];
  int b1 = seg[rs + RT - 1];
  int nu = (b1 - b0 + 1) * PS;
  for (int u = tid; u < nu; u += 256) {
    int bag = b0 + u / PS;
    int c   = u % PS;
    int sb  = segstart[bag];
    int lo  = max(sb, rs) - rs;
    int hi  = min(segstart[bag + 1], rs + RT) - rs;
    float m_ = -3.4e38f, se = 0.f, st = 0.f;
    for (int r = lo; r < hi; ++r) {
      float v  = res_u[r * 80 + c];
      float tv = f16tof(res_v[r * 80 + c]);
      float nm = fmaxf(m_, v);
      float sc = __expf(m_ - nm);
      float ee = __expf(v - nm);
      se = se * sc + ee;
      st = st * sc + ee * tv;
      m_ = nm;
    }
    int slot = blockIdx.x - (sb >> 6);
    size_t p = ((size_t)bag * NSLOT + slot) * PS + c;
    pm[p] = m_; pse[p] = se; pst[p] = st;
  }
}

// ---------------------------------------------------------------------------
// Kernel 2: MERGED combine + finalize (validated r13-r17; NSLOT=4, >>6).
// One block per column c (80 x 256). Slot-merge -> zsh[4096] + moments ->
// stats -> scaled write. Saves a launch + the zb global round-trip vs r12's
// separate combine_k/finalize_k.
// ---------------------------------------------------------------------------
__device__ inline float wave_sum(float v) {
#pragma unroll
  for (int o = 32; o > 0; o >>= 1) v += __shfl_down(v, o, 64);
  return v;
}

__global__ __launch_bounds__(256) void combfin_k(
    const int* __restrict__ segstart,
    const float* __restrict__ pm, const float* __restrict__ pse,
    const float* __restrict__ pst, const float* __restrict__ bz,
    float* __restrict__ out) {
  const int c = blockIdx.x;   // 0..79
  const int t = threadIdx.x;  // 0..255 (== Q rows for bz reduction)
  __shared__ float zsh[BB];   // 16 KB

  float bvz = bz[t * PS + c];
  float bsq = bvz * bvz;

  float s = 0.f, ss = 0.f;
  for (int b = t; b < BB; b += 256) {
    int sb = segstart[b], eb = segstart[b + 1];
    float z = 0.f;
    if (eb > sb) {
      int ns = ((eb - 1) >> 6) - (sb >> 6) + 1;
      ns = min(ns, NSLOT);
      float m = -3.4e38f, se = 0.f, st = 0.f;
      for (int sl = 0; sl < ns; ++sl) {
        size_t p = ((size_t)b * NSLOT + sl) * PS + c;
        float m2 = pm[p], se2 = pse[p], st2 = pst[p];
        float nm = fmaxf(m, m2);
        float s1 = __expf(m - nm);
        float s2 = __expf(m2 - nm);
        se = se * s1 + se2 * s2;
        st = st * s1 + st2 * s2;
        m = nm;
      }
      z = st / se;
    }
    zsh[b] = z;
    s += z;
    ss += z * z;
  }

  __shared__ float w0[4], w1[4], w2[4];
  float a0 = wave_sum(bsq);
  float a1 = wave_sum(s);
  float a2 = wave_sum(ss);
  int wid = t >> 6, lane = t & 63;
  if (lane == 0) { w0[wid] = a0; w1[wid] = a1; w2[wid] = a2; }
  __syncthreads();

  __shared__ float sh[3];
  if (t == 0) {
    float B0 = w0[0] + w0[1] + w0[2] + w0[3];
    float S1 = w1[0] + w1[1] + w1[2] + w1[3];
    float S2 = w2[0] + w2[1] + w2[2] + w2[3];
    float bval = sqrtf(B0 / (float)QQ);
    float mean = S1 / (float)BB;
    float var = (S2 - (float)BB * mean * mean) / (float)(BB - 1);
    float sd = sqrtf(fmaxf(var, 0.f));
    if (!(sd > 0.f) || sd != sd) sd = 1.f;
    sh[0] = bval; sh[1] = mean; sh[2] = sd;
  }
  __syncthreads();
  float bval = sh[0], mean = sh[1], sd = sh[2];
  for (int b = t; b < BB; b += 256) {
    out[b * PS + c] = bval * (zsh[b] - mean) / sd;
  }
}

// ---------------------------------------------------------------------------
extern "C" void kernel_launch(void* const* d_in, const int* in_sizes, int n_in,
                              void* d_out, int out_size, void* d_ws, size_t ws_size,
                              hipStream_t stream) {
  const float* x   = (const float*)d_in[0];
  const float* bu  = (const float*)d_in[1];
  const float* bz  = (const float*)d_in[2];
  const int*   seg = (const int*)d_in[3];   // harness narrows int64 -> int32
  float* out = (float*)d_out;

  // workspace layout (bytes):
  //   [0,     16640)  segstart (4097 ints, padded)
  //   [16640, 98560)  bFlat: 8*4*160*8 fp16 = 81920
  //   [98560, ...)    pm / pse / pst: BB*NSLOT*PS floats each
  char* ws = (char*)d_ws;
  int* segstart         = (int*)ws;
  unsigned short* bFlat = (unsigned short*)(ws + 16640);
  size_t pn  = (size_t)BB * NSLOT * PS;
  float* pm  = (float*)(ws + 98560);
  float* pse = pm + pn;
  float* pst = pse + pn;

  prep_k<<<(5120 + BB + 1 + 255) / 256, 256, 0, stream>>>(bu, bz, bFlat, seg, segstart);
  fused_k<<<NN / RT, 256, 0, stream>>>(x, bFlat, seg, segstart, pm, pse, pst);
  combfin_k<<<PS, 256, 0, stream>>>(segstart, pm, pse, pst, bz, out);
}

// Round 19
// 102.189 us; speedup vs baseline: 1.6582x; 1.1147x over previous
//
#include <hip/hip_runtime.h>
#include <hip/hip_bf16.h>
#include <math.h>

#define NN 262144
#define QQ 256
#define PS 80
#define BB 4096
#define NSLOT 4
#define RT 64             // rows per strip
#define NITER 8           // K tiles of 32
#define SMEM_BYTES 32768  // A-strip fp16 [8 kt][4 kg][64 row^swz][16B]; res union 30720

typedef _Float16 f16x8 __attribute__((ext_vector_type(8)));
typedef float f32x4  __attribute__((ext_vector_type(4)));

__device__ inline unsigned short f16b(float f) {
  return __builtin_bit_cast(unsigned short, (_Float16)f);
}
__device__ inline float f16tof(unsigned short u) {
  return (float)__builtin_bit_cast(_Float16, u);
}

// ---------------------------------------------------------------------------
// Kernel 0: B = [beta_u | beta_z] -> fp16 frag-coalesced bFlat[kt][kg][c][j]
// (kt<8, kg<4, c<160, j<8), elem k = kt*32+kg*8+j.  [validated r11/r12]
// ---------------------------------------------------------------------------
__global__ void bprep_k(const float* __restrict__ bu, const float* __restrict__ bz,
                        unsigned short* __restrict__ bFlat) {
  int gid = blockIdx.x * 256 + threadIdx.x;   // 5120 units
  if (gid >= 5120) return;
  int kt  = gid / 640;
  int rem = gid - kt * 640;
  int kg  = rem / 160;
  int c   = rem - kg * 160;
  unsigned short* dst = bFlat + (size_t)gid * 8;
  int kbase = kt * 32 + kg * 8;
#pragma unroll
  for (int j = 0; j < 8; ++j) {
    int k = kbase + j;
    float v = (c < PS) ? bu[k * PS + c] : bz[k * PS + (c - PS)];
    dst[j] = f16b(v);
  }
}

// ---------------------------------------------------------------------------
// Kernel 1: segment boundaries (seg_ids sorted, int32 from harness).
// ---------------------------------------------------------------------------
__global__ void seg_bounds_k(const int* __restrict__ seg, int* __restrict__ segstart) {
  int b = blockIdx.x * blockDim.x + threadIdx.x;
  if (b > BB) return;
  if (b == BB) { segstart[BB] = NN; return; }
  int lo = 0, hi = NN;
  while (lo < hi) {
    int mid = (lo + hi) >> 1;
    if (seg[mid] < b) lo = mid + 1; else hi = mid;
  }
  segstart[b] = lo;
}

// ---------------------------------------------------------------------------
// Kernel 2: FUSED fp16 MFMA GEMM (64x160x256) + segmented softmax-pool.
// CHAMPION STRUCTURE (r12, 101.3 us):
// Phase 1 (staging): ALL 16 x-float4 loads issued up front per thread
//   (64KB/block in flight -> HBM streaming), cvt f32->fp16, 8 uint4
//   ds_writes into [kt][kg][row^(kg<<2)][16B] (conflict-free). ONE barrier.
// Phase 2 (K-loop, NO barriers): 8 unrolled iters of
//   {2 ds_read_b128 A-frags, 10 MFMA}; B global->reg from L2-resident bFlat
//   (depth-2 slots, each slot reloaded AFTER its MFMA cluster).
// Phase 3: barrier, result->LDS (res union), barrier, in-LDS pool.
// Evidence r9-r18: every variant regresses (dbuf 105, vmcnt-counted 106,
// all-reg 138, split-half 119, quarter 123, 1-wave 169, async-chain 144,
// RT=32 134, merged-epilogue 114). Minimal-sync + coalesced epilogue wins.
// MFMA 16x16x32_f16: A row=lane&15, k=8*(lane>>4)+j; D col=lane&15,
// row=(lane>>4)*4+reg  [verified r3-r18].
// ---------------------------------------------------------------------------
__global__ __launch_bounds__(256, 4) void fused_k(
    const float* __restrict__ x, const unsigned short* __restrict__ bFlat,
    const int* __restrict__ seg, const int* __restrict__ segstart,
    float* __restrict__ pm, float* __restrict__ pse, float* __restrict__ pst) {
  __shared__ __align__(16) char smem[SMEM_BYTES];
  const int tid  = threadIdx.x;
  const int lane = tid & 63;
  const int wid  = tid >> 6;
  const int rs   = blockIdx.x * RT;

  const int wr   = (wid & 1) * 32;   // wave row offset
  const int cw   = wid >> 1;         // 0 -> u cols, 1 -> tz cols
  const int lrow = lane & 15;
  const int lk16 = lane >> 4;

  // ---------- Phase 1: stage whole x-strip (64 rows x 256 k) as fp16 ----------
  {
    const int ra = tid >> 2;         // 0..63
    const int kg = tid & 3;          // 0..3
    const float* xp = x + (size_t)(rs + ra) * QQ + kg * 8;
    float4 xs[16];
#pragma unroll
    for (int kt = 0; kt < NITER; ++kt) {
      xs[2 * kt]     = *reinterpret_cast<const float4*>(xp + kt * 32);
      xs[2 * kt + 1] = *reinterpret_cast<const float4*>(xp + kt * 32 + 4);
    }
    char* dst = smem + kg * 1024 + ((ra ^ (kg << 2)) * 16);
#pragma unroll
    for (int kt = 0; kt < NITER; ++kt) {
      float4 v0 = xs[2 * kt], v1 = xs[2 * kt + 1];
      unsigned short a0 = f16b(v0.x), a1 = f16b(v0.y), a2 = f16b(v0.z), a3 = f16b(v0.w);
      unsigned short a4 = f16b(v1.x), a5 = f16b(v1.y), a6 = f16b(v1.z), a7 = f16b(v1.w);
      uint4 w = make_uint4((unsigned)a0 | ((unsigned)a1 << 16),
                           (unsigned)a2 | ((unsigned)a3 << 16),
                           (unsigned)a4 | ((unsigned)a5 << 16),
                           (unsigned)a6 | ((unsigned)a7 << 16));
      *reinterpret_cast<uint4*>(dst + kt * 4096) = w;
    }
  }
  __syncthreads();

  // ---------- Phase 2: barrier-free K-loop ----------
  const unsigned short* bA = bFlat + ((size_t)lk16 * 160 + cw * 80 + lrow) * 8;
  const int aoff0 = lk16 * 1024 + (((wr + lrow)      ^ (lk16 << 2)) * 16);
  const int aoff1 = lk16 * 1024 + (((wr + 16 + lrow) ^ (lk16 << 2)) * 16);

  f16x8 br[2][5];
#define LOADB(s_, t_) do {                                                    \
    _Pragma("unroll")                                                         \
    for (int n_ = 0; n_ < 5; ++n_)                                            \
      br[s_][n_] = *reinterpret_cast<const f16x8*>(bA + (t_) * 5120 + n_ * 128); \
  } while (0)

  f32x4 acc[2][5];
#pragma unroll
  for (int m = 0; m < 2; ++m)
#pragma unroll
    for (int n = 0; n < 5; ++n) acc[m][n] = (f32x4){0.f, 0.f, 0.f, 0.f};

  LOADB(0, 0);
  LOADB(1, 1);

#pragma unroll
  for (int t = 0; t < NITER; ++t) {
    const int s = t & 1;
    f16x8 a0 = *reinterpret_cast<const f16x8*>(smem + t * 4096 + aoff0);
    f16x8 a1 = *reinterpret_cast<const f16x8*>(smem + t * 4096 + aoff1);
    __builtin_amdgcn_s_setprio(1);
#pragma unroll
    for (int n = 0; n < 5; ++n) {
      acc[0][n] = __builtin_amdgcn_mfma_f32_16x16x32_f16(a0, br[s][n], acc[0][n], 0, 0, 0);
      acc[1][n] = __builtin_amdgcn_mfma_f32_16x16x32_f16(a1, br[s][n], acc[1][n], 0, 0, 0);
    }
    __builtin_amdgcn_s_setprio(0);
    if (t < NITER - 2) LOADB(s, t + 2);   // reload slot AFTER its MFMA cluster
  }
#undef LOADB

  // ---------- Phase 3: result tile -> LDS (res union), pool ----------
  __syncthreads();   // all A ds_reads done before staging area is overwritten
  float* res_u          = reinterpret_cast<float*>(smem);                  // 20480
  unsigned short* res_v = reinterpret_cast<unsigned short*>(smem + 20480); // 10240
#pragma unroll
  for (int m = 0; m < 2; ++m)
#pragma unroll
    for (int n = 0; n < 5; ++n)
#pragma unroll
      for (int rr = 0; rr < 4; ++rr) {
        int row = wr + m * 16 + lk16 * 4 + rr;
        int col = n * 16 + lrow;
        if (cw == 0) res_u[row * 80 + col] = acc[m][n][rr];
        else         res_v[row * 80 + col] = f16b(acc[m][n][rr]);
      }
  __syncthreads();

  // segmented online softmax-pool over this 64-row strip
  int b0 = seg[rs];
  int b1 = seg[rs + RT - 1];
  int nu = (b1 - b0 + 1) * PS;
  for (int u = tid; u < nu; u += 256) {
    int bag = b0 + u / PS;
    int c   = u % PS;
    int sb  = segstart[bag];
    int lo  = max(sb, rs) - rs;
    int hi  = min(segstart[bag + 1], rs + RT) - rs;
    float m_ = -3.4e38f, se = 0.f, st = 0.f;
    for (int r = lo; r < hi; ++r) {
      float v  = res_u[r * 80 + c];
      float tv = f16tof(res_v[r * 80 + c]);
      float nm = fmaxf(m_, v);
      float sc = __expf(m_ - nm);
      float ee = __expf(v - nm);
      se = se * sc + ee;
      st = st * sc + ee * tv;
      m_ = nm;
    }
    int slot = blockIdx.x - (sb >> 6);
    size_t p = ((size_t)bag * NSLOT + slot) * PS + c;
    pm[p] = m_; pse[p] = se; pst[p] = st;
  }
}

// ---------------------------------------------------------------------------
// Kernel 3: merge partial slots per (bag,col) -> zb (= d_out).
// 1280 blocks, i = bag*80+c -> lanes read consecutive c -> COALESCED
// (r18 lesson: the 80-block merged version was uncoalesced, +12 us).
// ---------------------------------------------------------------------------
__global__ __launch_bounds__(256) void combine_k(
    const int* __restrict__ segstart,
    const float* __restrict__ pm, const float* __restrict__ pse,
    const float* __restrict__ pst, float* __restrict__ zb) {
  int i = blockIdx.x * 256 + threadIdx.x;   // BB*PS
  if (i >= BB * PS) return;
  int bag = i / PS, c = i % PS;
  int sb = segstart[bag], eb = segstart[bag + 1];
  float z = 0.f;
  if (eb > sb) {
    int ns = ((eb - 1) >> 6) - (sb >> 6) + 1;
    ns = min(ns, NSLOT);
    float m = -3.4e38f, se = 0.f, st = 0.f;
    for (int s = 0; s < ns; ++s) {
      size_t p = ((size_t)bag * NSLOT + s) * PS + c;
      float m2 = pm[p], se2 = pse[p], st2 = pst[p];
      float nm = fmaxf(m, m2);
      float s1 = __expf(m - nm);
      float s2 = __expf(m2 - nm);
      se = se * s1 + se2 * s2;
      st = st * s1 + st2 * s2;
      m = nm;
    }
    z = st / se;
  }
  zb[i] = z;
}

// ---------------------------------------------------------------------------
// Kernel 4: per-column stats + b-scale, IN PLACE on d_out.
// ---------------------------------------------------------------------------
__device__ inline float wave_sum(float v) {
#pragma unroll
  for (int o = 32; o > 0; o >>= 1) v += __shfl_down(v, o, 64);
  return v;
}

__global__ __launch_bounds__(256) void finalize_k(
    const float* __restrict__ bz, float* __restrict__ zb_out) {
  const int c = blockIdx.x;
  const int t = threadIdx.x;

  float bvz = bz[t * PS + c];
  float bsq = bvz * bvz;

  float s = 0.f, ss = 0.f;
  for (int b = t; b < BB; b += 256) {
    float z = zb_out[b * PS + c];
    s += z;
    ss += z * z;
  }

  __shared__ float w0[4], w1[4], w2[4];
  float a0 = wave_sum(bsq);
  float a1 = wave_sum(s);
  float a2 = wave_sum(ss);
  int wid = t >> 6, lane = t & 63;
  if (lane == 0) { w0[wid] = a0; w1[wid] = a1; w2[wid] = a2; }
  __syncthreads();

  __shared__ float sh[3];
  if (t == 0) {
    float B0 = w0[0] + w0[1] + w0[2] + w0[3];
    float S1 = w1[0] + w1[1] + w1[2] + w1[3];
    float S2 = w2[0] + w2[1] + w2[2] + w2[3];
    float bval = sqrtf(B0 / (float)QQ);
    float mean = S1 / (float)BB;
    float var = (S2 - (float)BB * mean * mean) / (float)(BB - 1);
    float sd = sqrtf(fmaxf(var, 0.f));
    if (!(sd > 0.f) || sd != sd) sd = 1.f;
    sh[0] = bval; sh[1] = mean; sh[2] = sd;
  }
  __syncthreads();
  float bval = sh[0], mean = sh[1], sd = sh[2];
  for (int b = t; b < BB; b += 256) {
    zb_out[b * PS + c] = bval * (zb_out[b * PS + c] - mean) / sd;
  }
}

// ---------------------------------------------------------------------------
extern "C" void kernel_launch(void* const* d_in, const int* in_sizes, int n_in,
                              void* d_out, int out_size, void* d_ws, size_t ws_size,
                              hipStream_t stream) {
  const float* x   = (const float*)d_in[0];
  const float* bu  = (const float*)d_in[1];
  const float* bz  = (const float*)d_in[2];
  const int*   seg = (const int*)d_in[3];   // harness narrows int64 -> int32
  float* out = (float*)d_out;

  // workspace layout (bytes):
  //   [0,     16640)  segstart (4097 ints, padded)
  //   [16640, 98560)  bFlat: 8*4*160*8 fp16 = 81920
  //   [98560, ...)    pm / pse / pst: BB*NSLOT*PS floats each
  char* ws = (char*)d_ws;
  int* segstart         = (int*)ws;
  unsigned short* bFlat = (unsigned short*)(ws + 16640);
  size_t pn  = (size_t)BB * NSLOT * PS;
  float* pm  = (float*)(ws + 98560);
  float* pse = pm + pn;
  float* pst = pse + pn;

  bprep_k<<<20, 256, 0, stream>>>(bu, bz, bFlat);
  seg_bounds_k<<<(BB + 1 + 255) / 256, 256, 0, stream>>>(seg, segstart);
  fused_k<<<NN / RT, 256, 0, stream>>>(x, bFlat, seg, segstart, pm, pse, pst);
  combine_k<<<(BB * PS + 255) / 256, 256, 0, stream>>>(segstart, pm, pse, pst, out);
  finalize_k<<<PS, 256, 0, stream>>>(bz, out);
}